// Round 1
// baseline (167.738 us; speedup 1.0000x reference)
//
#include <hip/hip_runtime.h>
#include <cmath>

typedef __attribute__((ext_vector_type(8))) short bf16x8;
typedef __attribute__((ext_vector_type(4))) short bf16x4;
typedef __attribute__((ext_vector_type(4))) float f32x4;

#define MFMA16(a,b,c)  __builtin_amdgcn_mfma_f32_16x16x32_bf16((a),(b),(c),0,0,0)
#define MFMA16K16(a,b,c) __builtin_amdgcn_mfma_f32_16x16x16bf16_1k((a),(b),(c),0,0,0)

#if __has_builtin(__builtin_amdgcn_exp2f)
#define EXP2F(x) __builtin_amdgcn_exp2f(x)
#else
#define EXP2F(x) exp2f(x)
#endif

// sqrt(128) * log2(e): folded into w_theta/b_theta at wcvt time.
#define KSCALE 16.3222312f

#define NB 4
#define CH 256
#define CI 128
#define NS 4096   // 64*64 spatial

__device__ __forceinline__ unsigned short f2bf(float f) {
    unsigned int u = __builtin_bit_cast(unsigned int, f);
    u += 0x7fffu + ((u >> 16) & 1u);           // RNE
    return (unsigned short)(u >> 16);
}
__device__ __forceinline__ unsigned int pk2(float lo, float hi) {
    return (unsigned int)f2bf(lo) | ((unsigned int)f2bf(hi) << 16);
}
// truncating pack (softmax P only)
__device__ __forceinline__ unsigned int pk2t(float lo, float hi) {
    unsigned int ul = __builtin_bit_cast(unsigned int, lo);
    unsigned int uh = __builtin_bit_cast(unsigned int, hi);
    return (uh & 0xffff0000u) | (ul >> 16);
}
__device__ __forceinline__ float bf2f(unsigned int ush) {   // low 16 bits
    return __builtin_bit_cast(float, ush << 16);
}

// async global->LDS 16B per lane: LDS dest = wave-uniform base + lane*16
__device__ __forceinline__ void gload16(void* lds, const void* g) {
    __builtin_amdgcn_global_load_lds(
        (const __attribute__((address_space(1))) unsigned int*)g,
        (__attribute__((address_space(3))) unsigned int*)lds,
        16, 0, 0);
}

// ---------------------------------------------------------------------------
// Kernel 0: one-time weight convert to bf16 (KSCALE folded into theta).
// ---------------------------------------------------------------------------
__global__ void wcvt_kernel(const float* __restrict__ w_g, const float* __restrict__ w_th,
                            const float* __restrict__ w_ph, const float* __restrict__ w_out,
                            const float* __restrict__ b_g, const float* __restrict__ b_th,
                            const float* __restrict__ b_ph,
                            unsigned short* __restrict__ wbf, float* __restrict__ bsc) {
    int i = blockIdx.x * 256 + threadIdx.x;     // 0..131071
    float v;
    if (i < 32768)        v = w_g[i];
    else if (i < 65536)   v = w_th[i - 32768] * KSCALE;
    else if (i < 98304)   v = w_ph[i - 65536];
    else                  v = w_out[i - 98304];
    wbf[i] = f2bf(v);
    if (i < 128)          bsc[i] = b_g[i];
    else if (i < 256)     bsc[i] = b_th[i - 128] * KSCALE;
    else if (i < 384)     bsc[i] = b_ph[i - 256];
}

// ---------------------------------------------------------------------------
// Kernel 1: FUSED projections — one x staging serves g/theta/phi (x read 1x).
// grid(64 s-tiles of 64, 4 n) = 256 blocks, 512 thr (8 waves).
// Waves: wid&3 -> s-quarter (16 rows), wid>>2 -> o-half (64 outputs).
// LDS x^T [64 s][128 c-pair uints] = 32 KB, column-group swizzle
// g' = g ^ ((row>>2)&7): staging writes hit all 32 banks; 16-lane spans of
// consecutive s4 give 256 B-contiguous global reads (verified correct in R6).
// ---------------------------------------------------------------------------
__global__ __launch_bounds__(512, 2)
void proj_kernel(const float* __restrict__ x,
                 const unsigned short* __restrict__ wbf, const float* __restrict__ bsc,
                 unsigned short* __restrict__ theta,
                 unsigned short* __restrict__ phi,
                 unsigned short* __restrict__ gT) {
    const int tid  = threadIdx.x;
    const int wid  = tid >> 6;         // 0..7
    const int lane = tid & 63;
    const int quad = lane >> 4;
    const int l15  = lane & 15;
    const int stile = blockIdx.x;      // 0..63
    const int n     = blockIdx.y;
    const int s0    = stile * 64;

    const float* xN = x + (size_t)n * CH * NS;

    __shared__ unsigned int xp[64 * 128];   // 32 KB, swizzled

    // stage: 2048 tasks (128 c-pairs x 16 s-spans of float4), 4/thread
#pragma unroll
    for (int i = 0; i < 4; i++) {
        int t  = i * 512 + tid;
        int s4 = t & 15;
        int cp = t >> 4;                    // 0..127
        const float* p0 = xN + (size_t)(2 * cp) * NS + s0 + s4 * 4;
        float4 a = *(const float4*)p0;
        float4 b = *(const float4*)(p0 + NS);
        int col = (((cp >> 2) ^ (s4 & 7)) << 2) | (cp & 3);   // row>>2 == s4
        unsigned int* xr = xp + (s4 * 4) * 128 + col;
        xr[0]   = pk2(a.x, b.x);
        xr[128] = pk2(a.y, b.y);
        xr[256] = pk2(a.z, b.z);
        xr[384] = pk2(a.w, b.w);
    }
    __syncthreads();

    const int srow = (wid & 3) * 16 + l15;
    const int oh   = wid >> 2;              // o-half
    const int sw7  = (srow >> 2) & 7;
#pragma unroll
    for (int wi = 0; wi < 3; wi++) {
        f32x4 acc[4];
#pragma unroll
        for (int ot = 0; ot < 4; ot++) acc[ot] = (f32x4){0.f, 0.f, 0.f, 0.f};
        const unsigned short* W = wbf + (size_t)wi * 32768 + (size_t)oh * 64 * CH;
#pragma unroll
        for (int kc = 0; kc < 8; kc++) {
            bf16x8 af = *(const bf16x8*)(&xp[srow * 128 + (((kc * 4 + quad) ^ sw7) << 2)]);
#pragma unroll
            for (int ot = 0; ot < 4; ot++) {
                bf16x8 wf = *(const bf16x8*)(W + (size_t)(ot * 16 + l15) * CH + kc * 32 + quad * 8);
                acc[ot] = MFMA16(af, wf, acc[ot]);
            }
        }
        const float* Bv = bsc + wi * 128 + oh * 64;
#pragma unroll
        for (int ot = 0; ot < 4; ot++) {
            int o = oh * 64 + ot * 16 + l15;
            float bias = Bv[ot * 16 + l15];
#pragma unroll
            for (int r = 0; r < 4; r++) {
                int sg = s0 + (wid & 3) * 16 + quad * 4 + r;
                float v = acc[ot][r] + bias;
                if (wi == 0)
                    gT[((size_t)n * CI + o) * NS + sg] = f2bf(v);
                else if (wi == 1)
                    theta[((size_t)n * NS + sg) * CI + o] = f2bf(v);
                else
                    phi[((size_t)n * NS + sg) * CI + o] = f2bf(v);
            }
        }
    }
}

// ---------------------------------------------------------------------------
// Kernel 2: flash attention partials.
// 256 thr (4 waves), q=32/wave, 64-s chunks, K/V double-buffer with
// prefetch-after-barrier.  NEW (this round): PV consumes P directly from
// registers via v_mfma_f32_16x16x16_bf16 — the K=16 A/B fragment k-span
// (quad*4+e) exactly matches the 16x16x32 D-fragment reg-span, so the
// exp2 outputs packed to bf16 ARE a valid fragment.  This removes the P
// LDS round-trip (8 ds_write_b64 + 4 ds_read_b128 + lgkm serialization
// per wave-chunk) and shrinks LDS 80->64 KB.  mfma(A=vf, B=pa) keeps
// D rows=c, cols=q -> O^T layout identical, epilogue unchanged.
// Softmax: p = exp2(S) (scale-invariant; no overflow).  O bf16 + l fp32.
// grid(16 = split*4+n, 32 qb) = 512 blocks.
// ---------------------------------------------------------------------------
__global__ __launch_bounds__(256, 2)
void attn_kernel(const unsigned short* __restrict__ theta,
                 const unsigned short* __restrict__ phi,
                 const unsigned short* __restrict__ gT,
                 unsigned short* __restrict__ Opart,
                 float* __restrict__ lbuf) {
    const int tid  = threadIdx.x;
    const int wid  = tid >> 6;          // 0..3
    const int lane = tid & 63;
    const int quad = lane >> 4;
    const int l15  = lane & 15;
    const int sn    = blockIdx.x;       // 0..15
    const int split = sn >> 2;          // 0..3
    const int n     = sn & 3;
    const int qb    = blockIdx.y;       // 0..31
    const int qbase = qb * 128 + wid * 32;

    const unsigned short* thN = theta + (size_t)n * NS * CI;
    const unsigned short* phN = phi   + (size_t)n * NS * CI;
    const unsigned short* gN  = gT    + (size_t)n * CI * NS;

    // K dbuf: 2 x [64 s][128 c] (chunk ^ (s&15))   32 KB
    // V dbuf: 2 x [128 c][64 s] (chunk ^ (c&7))    32 KB     total 64 KB
    __shared__ unsigned short smem[32768];
    unsigned short* Kb = smem;              // + cur*8192
    unsigned short* Vb = smem + 16384;      // + cur*8192

    bf16x8 qf[2][4];
#pragma unroll
    for (int qt = 0; qt < 2; qt++)
#pragma unroll
        for (int kc = 0; kc < 4; kc++)
            qf[qt][kc] = *(const bf16x8*)(thN + (size_t)(qbase + qt * 16 + l15) * CI + kc * 32 + quad * 8);

    f32x4 O[8][2];    // O^T tiles [ct][qt]: row=c, col=q
#pragma unroll
    for (int ct = 0; ct < 8; ct++)
#pragma unroll
        for (int qt = 0; qt < 2; qt++) O[ct][qt] = (f32x4){0.f, 0.f, 0.f, 0.f};
    float lrun[2] = {0.f, 0.f};

    const int sbase0 = split * 1024;
    const int lh16 = lane >> 4, lm16 = lane & 15;
    const int lh8  = lane >> 3, lm8  = lane & 7;

    // stage chunk 0 -> buffer 0 (4 K segs + 4 V segs per wave)
#pragma unroll
    for (int i = 0; i < 4; i++) {
        int seg = wid * 4 + i;                  // 0..15
        int s   = seg * 4 + lh16;               // 0..63
        int j   = lm16 ^ (s & 15);
        gload16(Kb + seg * 512, phN + (size_t)(sbase0 + s) * CI + j * 8);
    }
#pragma unroll
    for (int i = 0; i < 4; i++) {
        int seg = wid * 4 + i;
        int c   = seg * 8 + lh8;                // 0..127
        int j   = lm8 ^ (c & 7);
        gload16(Vb + seg * 512, gN + (size_t)c * NS + sbase0 + j * 8);
    }

    for (int ck = 0; ck < 16; ck++) {
        const int cur = ck & 1, nxt = cur ^ 1;
        unsigned short* Kc = Kb + cur * 8192;
        unsigned short* Vc = Vb + cur * 8192;
        __syncthreads();    // drains cur loads; prev compute done

        if (ck + 1 < 16) {  // async prefetch next chunk
            const int sb1 = sbase0 + (ck + 1) * 64;
#pragma unroll
            for (int i = 0; i < 4; i++) {
                int seg = wid * 4 + i;
                int s   = seg * 4 + lh16;
                int j   = lm16 ^ (s & 15);
                gload16(Kb + nxt * 8192 + seg * 512, phN + (size_t)(sb1 + s) * CI + j * 8);
            }
#pragma unroll
            for (int i = 0; i < 4; i++) {
                int seg = wid * 4 + i;
                int c   = seg * 8 + lh8;
                int j   = lm8 ^ (c & 7);
                gload16(Vb + nxt * 8192 + seg * 512, gN + (size_t)c * NS + sb1 + j * 8);
            }
        }

        // QK^T -> S^T[qt][st]
        f32x4 S[2][4];
#pragma unroll
        for (int qt = 0; qt < 2; qt++)
#pragma unroll
            for (int st = 0; st < 4; st++) S[qt][st] = (f32x4){0.f, 0.f, 0.f, 0.f};
        __builtin_amdgcn_s_setprio(1);
#pragma unroll
        for (int st = 0; st < 4; st++) {
#pragma unroll
            for (int kc = 0; kc < 4; kc++) {
                int s = st * 16 + l15;
                bf16x8 kf = *(const bf16x8*)(Kc + s * 128 + ((kc * 4 + quad) ^ l15) * 8);
#pragma unroll
                for (int qt = 0; qt < 2; qt++)
                    S[qt][st] = MFMA16(kf, qf[qt][kc], S[qt][st]);
            }
        }
        __builtin_amdgcn_s_setprio(0);

        // softmax: p = exp2(S), packed in-register as K=16 fragments.
        // pa[qt][st] holds P[q=l15][s = st*16 + quad*4 + e], e=0..3 — exactly
        // the 16x16x16 fragment layout (row/col=l15, k=quad*4+e).
        bf16x4 pa[2][4];
#pragma unroll
        for (int qt = 0; qt < 2; qt++) {
            float rsl = 0.f;
#pragma unroll
            for (int st = 0; st < 4; st++) {
                float p0 = EXP2F(S[qt][st][0]);
                float p1 = EXP2F(S[qt][st][1]);
                float p2 = EXP2F(S[qt][st][2]);
                float p3 = EXP2F(S[qt][st][3]);
                rsl += (p0 + p1) + (p2 + p3);
                union { unsigned int uu[2]; bf16x4 v; } pkv;
                pkv.uu[0] = pk2t(p0, p1);
                pkv.uu[1] = pk2t(p2, p3);
                pa[qt][st] = pkv.v;
            }
            lrun[qt] += rsl;
        }

        // PV: O^T += V^T . P^T over 4 K=16 slices (P from registers).
        // V b64 read: s-range st*16 + quad*4, group g = (st*2 + (quad>>1)),
        // same ^(c&7) swizzle as staging; conflict-free by construction.
        __builtin_amdgcn_s_setprio(1);
#pragma unroll
        for (int st = 0; st < 4; st++) {
            const int g = (st * 2 + (quad >> 1)) ^ (l15 & 7);
            const int so = g * 8 + (quad & 1) * 4;
#pragma unroll
            for (int ct = 0; ct < 8; ct++) {
                bf16x4 vf = *(const bf16x4*)(Vc + (ct * 16 + l15) * 64 + so);
#pragma unroll
                for (int qt = 0; qt < 2; qt++)
                    O[ct][qt] = MFMA16K16(vf, pa[qt][st], O[ct][qt]);
            }
        }
        __builtin_amdgcn_s_setprio(0);
    }

    // epilogue: O^T -> Opart[q][c] bf16 (uint4 stores) via per-wave transpose
    __syncthreads();
    float* tb = (float*)smem + wid * 2048;   // 4 waves x 8 KB (K/V region)
    const size_t obase = ((size_t)(split * NB + n)) * NS * CI;
#pragma unroll
    for (int qt = 0; qt < 2; qt++) {
#pragma unroll
        for (int ct = 0; ct < 8; ct++) {
            int p = (ct * 4 + quad) ^ l15;
            *(f32x4*)(tb + l15 * 128 + p * 4) = O[ct][qt];
        }
#pragma unroll
        for (int i = 0; i < 4; i++) {
            int flat = i * 64 + lane;
            int row = flat >> 4, jj = flat & 15;
            f32x4 a = *(const f32x4*)(tb + row * 128 + ((jj * 2) ^ row) * 4);
            f32x4 b = *(const f32x4*)(tb + row * 128 + ((jj * 2 + 1) ^ row) * 4);
            int q = qbase + qt * 16 + row;
            uint4 pkv;
            pkv.x = pk2(a[0], a[1]); pkv.y = pk2(a[2], a[3]);
            pkv.z = pk2(b[0], b[1]); pkv.w = pk2(b[2], b[3]);
            *(uint4*)(Opart + obase + (size_t)q * CI + jj * 8) = pkv;
        }
        __syncthreads();   // tb reused across qt by all waves' reads above
    }
    lrun[0] += __shfl_xor(lrun[0], 16); lrun[0] += __shfl_xor(lrun[0], 32);
    lrun[1] += __shfl_xor(lrun[1], 16); lrun[1] += __shfl_xor(lrun[1], 32);
    if (quad == 0) {
#pragma unroll
        for (int qt = 0; qt < 2; qt++) {
            int q = qbase + qt * 16 + l15;
            lbuf[(split * NB + n) * NS + q] = lrun[qt];
        }
    }
}

// ---------------------------------------------------------------------------
// Kernel 3: fused merge (4 bf16 partials) + output projection + residual.
// grid(64 s-tiles, 2 o-halves, 4 n) = 512 blocks, 256 thr.
// ---------------------------------------------------------------------------
__global__ __launch_bounds__(256, 4)
void outproj_kernel(const float* __restrict__ x,
                    const unsigned short* __restrict__ wbf,
                    const float* __restrict__ b_out,
                    const unsigned short* __restrict__ Opart,
                    const float* __restrict__ lbuf,
                    float* __restrict__ out) {
    const int tid  = threadIdx.x;
    const int wid  = tid >> 6;
    const int lane = tid & 63;
    const int quad = lane >> 4;
    const int l15  = lane & 15;
    const int oh = blockIdx.y;
    const int n  = blockIdx.z;
    const int sw = blockIdx.x * 64 + wid * 16;
    const int T  = NB * NS;

    const int srow = n * NS + sw + l15;
    float l = 0.f;
#pragma unroll
    for (int k = 0; k < 4; k++) l += lbuf[k * T + srow];
    float rinv = 1.0f / l;

    bf16x8 yb[4];
#pragma unroll
    for (int kc = 0; kc < 4; kc++) {
        float f0 = 0.f, f1 = 0.f, f2 = 0.f, f3 = 0.f;
        float f4 = 0.f, f5 = 0.f, f6 = 0.f, f7 = 0.f;
#pragma unroll
        for (int k = 0; k < 4; k++) {
            uint4 v = *(const uint4*)(Opart + ((size_t)k * T + srow) * CI + kc * 32 + quad * 8);
            f0 += bf2f(v.x & 0xffffu); f1 += bf2f(v.x >> 16);
            f2 += bf2f(v.y & 0xffffu); f3 += bf2f(v.y >> 16);
            f4 += bf2f(v.z & 0xffffu); f5 += bf2f(v.z >> 16);
            f6 += bf2f(v.w & 0xffffu); f7 += bf2f(v.w >> 16);
        }
        union { unsigned int uu[4]; bf16x8 vv; } r;
        r.uu[0] = pk2(f0 * rinv, f1 * rinv);
        r.uu[1] = pk2(f2 * rinv, f3 * rinv);
        r.uu[2] = pk2(f4 * rinv, f5 * rinv);
        r.uu[3] = pk2(f6 * rinv, f7 * rinv);
        yb[kc] = r.vv;
    }

    const unsigned short* wob = wbf + 3 * 32768 + (size_t)oh * 128 * CI;
    f32x4 acc[8];
#pragma unroll
    for (int ot = 0; ot < 8; ot++) acc[ot] = (f32x4){0.f, 0.f, 0.f, 0.f};
#pragma unroll
    for (int kc = 0; kc < 4; kc++) {
#pragma unroll
        for (int ot = 0; ot < 8; ot++) {
            bf16x8 wa = *(const bf16x8*)(wob + (size_t)(ot * 16 + l15) * CI + kc * 32 + quad * 8);
            acc[ot] = MFMA16(wa, yb[kc], acc[ot]);
        }
    }
#pragma unroll
    for (int ot = 0; ot < 8; ot++) {
#pragma unroll
        for (int r = 0; r < 4; r++) {
            int o = oh * 128 + ot * 16 + quad * 4 + r;
            size_t idx = ((size_t)n * CH + o) * NS + sw + l15;
            out[idx] = x[idx] + acc[ot][r] + b_out[o];
        }
    }
}

// ---------------------------------------------------------------------------
extern "C" void kernel_launch(void* const* d_in, const int* in_sizes, int n_in,
                              void* d_out, int out_size, void* d_ws, size_t ws_size,
                              hipStream_t stream) {
    const float* x     = (const float*)d_in[0];
    const float* w_g   = (const float*)d_in[1];
    const float* b_g   = (const float*)d_in[2];
    const float* w_th  = (const float*)d_in[3];
    const float* b_th  = (const float*)d_in[4];
    const float* w_ph  = (const float*)d_in[5];
    const float* b_ph  = (const float*)d_in[6];
    const float* w_out = (const float*)d_in[7];
    const float* b_out = (const float*)d_in[8];
    float* out = (float*)d_out;

    char* ws = (char*)d_ws;
    unsigned short* theta = (unsigned short*)(ws + 0);          //  4 MiB
    unsigned short* phi   = (unsigned short*)(ws + 4194304);    //  4 MiB
    unsigned short* gT    = (unsigned short*)(ws + 8388608);    //  4 MiB
    unsigned short* Opart = (unsigned short*)(ws + 12582912);   // 16 MiB (4 splits bf16)
    float* lbuf  = (float*)(ws + 29360128);                     // 256 KiB
    unsigned short* wbf = (unsigned short*)(ws + 29622272);     // 256 KiB
    float* bsc   = (float*)(ws + 29884416);                     //  1.5 KiB

    wcvt_kernel<<<512, 256, 0, stream>>>(w_g, w_th, w_ph, w_out, b_g, b_th, b_ph, wbf, bsc);
    proj_kernel<<<dim3(64, NB), 512, 0, stream>>>(x, wbf, bsc, theta, phi, gT);
    attn_kernel<<<dim3(16, 32), 256, 0, stream>>>(theta, phi, gT, Opart, lbuf);
    outproj_kernel<<<dim3(64, 2, NB), 256, 0, stream>>>(x, wbf, b_out, Opart, lbuf, out);
}

// Round 3
// 160.446 us; speedup vs baseline: 1.0454x; 1.0454x over previous
//
#include <hip/hip_runtime.h>
#include <cmath>

typedef __attribute__((ext_vector_type(8))) short bf16x8;
typedef __attribute__((ext_vector_type(4))) float f32x4;
typedef __attribute__((ext_vector_type(16))) float f32x16;

#define MFMA16(a,b,c)  __builtin_amdgcn_mfma_f32_16x16x32_bf16((a),(b),(c),0,0,0)
#define MFMA32(a,b,c)  __builtin_amdgcn_mfma_f32_32x32x16_bf16((a),(b),(c),0,0,0)

#if __has_builtin(__builtin_amdgcn_exp2f)
#define EXP2F(x) __builtin_amdgcn_exp2f(x)
#else
#define EXP2F(x) exp2f(x)
#endif

// sqrt(128) * log2(e): folded into w_theta/b_theta at wcvt time.
#define KSCALE 16.3222312f

#define NB 4
#define CH 256
#define CI 128
#define NS 4096   // 64*64 spatial

__device__ __forceinline__ unsigned short f2bf(float f) {
    unsigned int u = __builtin_bit_cast(unsigned int, f);
    u += 0x7fffu + ((u >> 16) & 1u);           // RNE
    return (unsigned short)(u >> 16);
}
__device__ __forceinline__ unsigned int pk2(float lo, float hi) {
    return (unsigned int)f2bf(lo) | ((unsigned int)f2bf(hi) << 16);
}
// truncating pack (softmax P only): 1-op v_perm_b32
__device__ __forceinline__ unsigned int pkt(float lo, float hi) {
    return __builtin_amdgcn_perm(__builtin_bit_cast(unsigned int, hi),
                                 __builtin_bit_cast(unsigned int, lo), 0x07060302u);
}
__device__ __forceinline__ float bf2f(unsigned int ush) {   // low 16 bits
    return __builtin_bit_cast(float, ush << 16);
}

// Half-exchange for P-fragment assembly (see attn_kernel).
// v_permlane32_swap_b32 vdst, vsrc:  vdst' hi-lanes <- vsrc lo-lanes,
// vsrc' lo-lanes <- vdst hi-lanes (direction pinned by the HW-verified
// T12/m214 recipe).  Inline asm removes any builtin return-order ambiguity:
// operand 0 IS vdst, both modified in place.
// Call as plswap(wLow, wHigh):
//   in : wLow  = even-g word, lane-half h holds s16 (4h+m0, 4h+m0+1)
//        wHigh = odd-g  word, lane-half h holds s16 (8+4h+m0, 8+4h+m0+1)
//   out: wLow  = fragment k-low word  (e = m0,m0+1):  h0 s(m0,..), h1 s(8+m0,..)
//        wHigh = fragment k-high word (e = 4+m0,..):  h0 s(4+m0,..), h1 s(12+m0,..)
__device__ __forceinline__ void plswap(unsigned int& wLow, unsigned int& wHigh) {
    asm volatile("v_permlane32_swap_b32 %0, %1" : "+v"(wLow), "+v"(wHigh));
}

__device__ __forceinline__ f32x16 zero16() {
    f32x16 v;
#pragma unroll
    for (int i = 0; i < 16; i++) v[i] = 0.f;
    return v;
}

// async global->LDS 16B per lane: LDS dest = wave-uniform base + lane*16
__device__ __forceinline__ void gload16(void* lds, const void* g) {
    __builtin_amdgcn_global_load_lds(
        (const __attribute__((address_space(1))) unsigned int*)g,
        (__attribute__((address_space(3))) unsigned int*)lds,
        16, 0, 0);
}

// ---------------------------------------------------------------------------
// Kernel 0: one-time weight convert to bf16 (KSCALE folded into theta).
// ---------------------------------------------------------------------------
__global__ void wcvt_kernel(const float* __restrict__ w_g, const float* __restrict__ w_th,
                            const float* __restrict__ w_ph, const float* __restrict__ w_out,
                            const float* __restrict__ b_g, const float* __restrict__ b_th,
                            const float* __restrict__ b_ph,
                            unsigned short* __restrict__ wbf, float* __restrict__ bsc) {
    int i = blockIdx.x * 256 + threadIdx.x;     // 0..131071
    float v;
    if (i < 32768)        v = w_g[i];
    else if (i < 65536)   v = w_th[i - 32768] * KSCALE;
    else if (i < 98304)   v = w_ph[i - 65536];
    else                  v = w_out[i - 98304];
    wbf[i] = f2bf(v);
    if (i < 128)          bsc[i] = b_g[i];
    else if (i < 256)     bsc[i] = b_th[i - 128] * KSCALE;
    else if (i < 384)     bsc[i] = b_ph[i - 256];
}

// ---------------------------------------------------------------------------
// Kernel 1: FUSED projections — one x staging serves g/theta/phi (x read 1x).
// grid(64 s-tiles of 64, 4 n) = 256 blocks, 512 thr (8 waves).
// ---------------------------------------------------------------------------
__global__ __launch_bounds__(512, 2)
void proj_kernel(const float* __restrict__ x,
                 const unsigned short* __restrict__ wbf, const float* __restrict__ bsc,
                 unsigned short* __restrict__ theta,
                 unsigned short* __restrict__ phi,
                 unsigned short* __restrict__ gT) {
    const int tid  = threadIdx.x;
    const int wid  = tid >> 6;         // 0..7
    const int lane = tid & 63;
    const int quad = lane >> 4;
    const int l15  = lane & 15;
    const int stile = blockIdx.x;      // 0..63
    const int n     = blockIdx.y;
    const int s0    = stile * 64;

    const float* xN = x + (size_t)n * CH * NS;

    __shared__ unsigned int xp[64 * 128];   // 32 KB, swizzled

    // stage: 2048 tasks (128 c-pairs x 16 s-spans of float4), 4/thread
#pragma unroll
    for (int i = 0; i < 4; i++) {
        int t  = i * 512 + tid;
        int s4 = t & 15;
        int cp = t >> 4;                    // 0..127
        const float* p0 = xN + (size_t)(2 * cp) * NS + s0 + s4 * 4;
        float4 a = *(const float4*)p0;
        float4 b = *(const float4*)(p0 + NS);
        int col = (((cp >> 2) ^ (s4 & 7)) << 2) | (cp & 3);   // row>>2 == s4
        unsigned int* xr = xp + (s4 * 4) * 128 + col;
        xr[0]   = pk2(a.x, b.x);
        xr[128] = pk2(a.y, b.y);
        xr[256] = pk2(a.z, b.z);
        xr[384] = pk2(a.w, b.w);
    }
    __syncthreads();

    const int srow = (wid & 3) * 16 + l15;
    const int oh   = wid >> 2;              // o-half
    const int sw7  = (srow >> 2) & 7;
#pragma unroll
    for (int wi = 0; wi < 3; wi++) {
        f32x4 acc[4];
#pragma unroll
        for (int ot = 0; ot < 4; ot++) acc[ot] = (f32x4){0.f, 0.f, 0.f, 0.f};
        const unsigned short* W = wbf + (size_t)wi * 32768 + (size_t)oh * 64 * CH;
#pragma unroll
        for (int kc = 0; kc < 8; kc++) {
            bf16x8 af = *(const bf16x8*)(&xp[srow * 128 + (((kc * 4 + quad) ^ sw7) << 2)]);
#pragma unroll
            for (int ot = 0; ot < 4; ot++) {
                bf16x8 wf = *(const bf16x8*)(W + (size_t)(ot * 16 + l15) * CH + kc * 32 + quad * 8);
                acc[ot] = MFMA16(af, wf, acc[ot]);
            }
        }
        const float* Bv = bsc + wi * 128 + oh * 64;
#pragma unroll
        for (int ot = 0; ot < 4; ot++) {
            int o = oh * 64 + ot * 16 + l15;
            float bias = Bv[ot * 16 + l15];
#pragma unroll
            for (int r = 0; r < 4; r++) {
                int sg = s0 + (wid & 3) * 16 + quad * 4 + r;
                float v = acc[ot][r] + bias;
                if (wi == 0)
                    gT[((size_t)n * CI + o) * NS + sg] = f2bf(v);
                else if (wi == 1)
                    theta[((size_t)n * NS + sg) * CI + o] = f2bf(v);
                else
                    phi[((size_t)n * NS + sg) * CI + o] = f2bf(v);
            }
        }
    }
}

// ---------------------------------------------------------------------------
// Kernel 2: flash attention partials — 32x32x16 structure (R2) with the
// permlane32_swap direction/ordering FIXED (inline asm, args = (low, high)).
// 256 thr (4 waves), q=32/wave, 64-s chunks, K/V double-buffer, 64 KB LDS.
//
// QK^T: A=K(32 s rows), B=Q(32 q cols), 8 c-slices of 16 -> S^T 32x32.
//   D layout: q = lane&31, s_local = (reg&3) + 8*(reg>>2) + 4*(lane>>5).
// Softmax in-register; P assembled into 32x32x16 B-fragments (k = s) with
//   one v_permlane32_swap per word pair — no LDS P round-trip.
// PV: A=V(32 c rows), B=P -> O^T accumulated, full-rate 32x32x16.
// grid(16 = split*4+n, 32 qb) = 512 blocks.
// ---------------------------------------------------------------------------
__global__ __launch_bounds__(256, 2)
void attn_kernel(const unsigned short* __restrict__ theta,
                 const unsigned short* __restrict__ phi,
                 const unsigned short* __restrict__ gT,
                 unsigned short* __restrict__ Opart,
                 float* __restrict__ lbuf) {
    const int tid  = threadIdx.x;
    const int wid  = tid >> 6;          // 0..3
    const int lane = tid & 63;
    const int l31  = lane & 31;
    const int lh32 = lane >> 5;         // 0..1
    const int sn    = blockIdx.x;       // 0..15
    const int split = sn >> 2;          // 0..3
    const int n     = sn & 3;
    const int qb    = blockIdx.y;       // 0..31
    const int qbase = qb * 128 + wid * 32;

    const unsigned short* thN = theta + (size_t)n * NS * CI;
    const unsigned short* phN = phi   + (size_t)n * NS * CI;
    const unsigned short* gN  = gT    + (size_t)n * CI * NS;

    // K dbuf: 2 x [64 s][128 c] (slot ^ (s&15))   32 KB
    // V dbuf: 2 x [128 c][64 s] (slot ^ (c&7))    32 KB     total 64 KB
    __shared__ unsigned short smem[32768];
    unsigned short* Kb = smem;              // + cur*8192
    unsigned short* Vb = smem + 16384;      // + cur*8192

    // Q B-fragments: col = q = l31, k = lh32*8 + e within each 16-c slice
    bf16x8 qf[8];
#pragma unroll
    for (int kc = 0; kc < 8; kc++)
        qf[kc] = *(const bf16x8*)(thN + (size_t)(qbase + l31) * CI + kc * 16 + lh32 * 8);

    f32x16 O[4];    // O^T tiles: row c = ct*32 + (reg&3)+8*(reg>>2)+4*lh32, col q = l31
#pragma unroll
    for (int ct = 0; ct < 4; ct++) O[ct] = zero16();
    float lrun = 0.f;

    const int sbase0 = split * 1024;
    const int lh16 = lane >> 4, lm16 = lane & 15;
    const int lh8  = lane >> 3, lm8  = lane & 7;

    // stage chunk 0 -> buffer 0 (4 K segs + 4 V segs per wave)
#pragma unroll
    for (int i = 0; i < 4; i++) {
        int seg = wid * 4 + i;                  // 0..15
        int s   = seg * 4 + lh16;               // 0..63
        int j   = lm16 ^ (s & 15);
        gload16(Kb + seg * 512, phN + (size_t)(sbase0 + s) * CI + j * 8);
    }
#pragma unroll
    for (int i = 0; i < 4; i++) {
        int seg = wid * 4 + i;
        int c   = seg * 8 + lh8;                // 0..127
        int j   = lm8 ^ (c & 7);
        gload16(Vb + seg * 512, gN + (size_t)c * NS + sbase0 + j * 8);
    }

    for (int ck = 0; ck < 16; ck++) {
        const int cur = ck & 1, nxt = cur ^ 1;
        unsigned short* Kc = Kb + cur * 8192;
        unsigned short* Vc = Vb + cur * 8192;
        __syncthreads();    // drains cur loads; prev compute done

        if (ck + 1 < 16) {  // async prefetch next chunk
            const int sb1 = sbase0 + (ck + 1) * 64;
#pragma unroll
            for (int i = 0; i < 4; i++) {
                int seg = wid * 4 + i;
                int s   = seg * 4 + lh16;
                int j   = lm16 ^ (s & 15);
                gload16(Kb + nxt * 8192 + seg * 512, phN + (size_t)(sb1 + s) * CI + j * 8);
            }
#pragma unroll
            for (int i = 0; i < 4; i++) {
                int seg = wid * 4 + i;
                int c   = seg * 8 + lh8;
                int j   = lm8 ^ (c & 7);
                gload16(Vb + nxt * 8192 + seg * 512, gN + (size_t)c * NS + sb1 + j * 8);
            }
        }

        // QK^T -> S^T: 2 s-blocks x 8 c-slices
        f32x16 S[2];
        S[0] = zero16(); S[1] = zero16();
        __builtin_amdgcn_s_setprio(1);
#pragma unroll
        for (int sb = 0; sb < 2; sb++) {
#pragma unroll
            for (int kc = 0; kc < 8; kc++) {
                int s = sb * 32 + l31;
                bf16x8 kf = *(const bf16x8*)(Kc + s * 128 + (((kc * 2 + lh32) ^ (s & 15)) * 8));
                S[sb] = MFMA32(kf, qf[kc], S[sb]);
            }
        }
        __builtin_amdgcn_s_setprio(0);

        // softmax: p = exp2(S); assemble P B-fragments (k=s) per 16-s slice.
        // Lane-half h holds s16 = m + 8*(g&1) + 4*h for reg-group pair
        // g = {2b, 2b+1}; fragment needs k = h*8 + e.  One plswap per
        // (even,odd) word pair: outputs are the k-low / k-high words.
        bf16x8 pf[4];
        float lsum = 0.f;
#pragma unroll
        for (int ks = 0; ks < 4; ks++) {
            const int sb = ks >> 1, b = ks & 1;
            float pA[4], pB[4];
#pragma unroll
            for (int m = 0; m < 4; m++) {
                pA[m] = EXP2F(S[sb][(2 * b) * 4 + m]);       // even g: s16 = m+4h
                pB[m] = EXP2F(S[sb][(2 * b + 1) * 4 + m]);   // odd g:  s16 = 8+m+4h
            }
            lsum += ((pA[0] + pA[1]) + (pA[2] + pA[3]))
                  + ((pB[0] + pB[1]) + (pB[2] + pB[3]));
            unsigned int wA0 = pkt(pA[0], pA[1]);   // low word,  m0=0
            unsigned int wA1 = pkt(pA[2], pA[3]);   // low word,  m0=2
            unsigned int wB0 = pkt(pB[0], pB[1]);   // high word, m0=0
            unsigned int wB1 = pkt(pB[2], pB[3]);   // high word, m0=2
            plswap(wA0, wB0);   // wA0 -> u0 (e0,1), wB0 -> u2 (e4,5)
            plswap(wA1, wB1);   // wA1 -> u1 (e2,3), wB1 -> u3 (e6,7)
            union { unsigned int u[4]; bf16x8 v; } P;
            P.u[0] = wA0; P.u[1] = wA1; P.u[2] = wB0; P.u[3] = wB1;
            pf[ks] = P.v;
        }
        lrun += lsum;

        // PV: O^T += V^T . P^T over 4 K=16 slices (P from registers).
        __builtin_amdgcn_s_setprio(1);
#pragma unroll
        for (int ks = 0; ks < 4; ks++) {
#pragma unroll
            for (int ct = 0; ct < 4; ct++) {
                int c = ct * 32 + l31;
                bf16x8 vf = *(const bf16x8*)(Vc + c * 64 + (((ks * 2 + lh32) ^ (c & 7)) * 8));
                O[ct] = MFMA32(vf, pf[ks], O[ct]);
            }
        }
        __builtin_amdgcn_s_setprio(0);
    }

    // epilogue: O^T (32x32 tiles) -> Opart[q][c] bf16 via per-wave LDS
    // transpose, 2 passes of 2 ct (8 KB tb per wave), XOR-swizzled 16B slots.
    __syncthreads();
    float* tb = (float*)smem + wid * 2048;   // 4 waves x 8 KB
    const size_t obase = ((size_t)(split * NB + n)) * NS * CI;
#pragma unroll
    for (int pass = 0; pass < 2; pass++) {
#pragma unroll
        for (int cti = 0; cti < 2; cti++) {
            const int ct = pass * 2 + cti;
#pragma unroll
            for (int g = 0; g < 4; g++) {
                const int c_local = cti * 32 + 8 * g + 4 * lh32;   // +0..3
                const int slot = (c_local >> 2) ^ (l31 & 15);
                f32x4 v;
                v[0] = O[ct][4 * g + 0]; v[1] = O[ct][4 * g + 1];
                v[2] = O[ct][4 * g + 2]; v[3] = O[ct][4 * g + 3];
                *(f32x4*)(tb + l31 * 64 + slot * 4) = v;
            }
        }
#pragma unroll
        for (int i = 0; i < 8; i++) {
            const int qr  = i * 4 + (lane >> 4);    // 0..31
            const int lin = lane & 15;
            f32x4 v = *(const f32x4*)(tb + qr * 64 + ((lin ^ (qr & 15)) * 4));
            uint2 w;
            w.x = pk2(v[0], v[1]);
            w.y = pk2(v[2], v[3]);
            *(uint2*)(Opart + obase + (size_t)(qbase + qr) * CI + pass * 64 + lin * 4) = w;
        }
    }
    lrun += __shfl_xor(lrun, 32);
    if (lane < 32)
        lbuf[(split * NB + n) * NS + qbase + l31] = lrun;
}

// ---------------------------------------------------------------------------
// Kernel 3: fused merge (4 bf16 partials) + output projection + residual.
// grid(64 s-tiles, 2 o-halves, 4 n) = 512 blocks, 256 thr.
// ---------------------------------------------------------------------------
__global__ __launch_bounds__(256, 4)
void outproj_kernel(const float* __restrict__ x,
                    const unsigned short* __restrict__ wbf,
                    const float* __restrict__ b_out,
                    const unsigned short* __restrict__ Opart,
                    const float* __restrict__ lbuf,
                    float* __restrict__ out) {
    const int tid  = threadIdx.x;
    const int wid  = tid >> 6;
    const int lane = tid & 63;
    const int quad = lane >> 4;
    const int l15  = lane & 15;
    const int oh = blockIdx.y;
    const int n  = blockIdx.z;
    const int sw = blockIdx.x * 64 + wid * 16;
    const int T  = NB * NS;

    const int srow = n * NS + sw + l15;
    float l = 0.f;
#pragma unroll
    for (int k = 0; k < 4; k++) l += lbuf[k * T + srow];
    float rinv = 1.0f / l;

    bf16x8 yb[4];
#pragma unroll
    for (int kc = 0; kc < 4; kc++) {
        float f0 = 0.f, f1 = 0.f, f2 = 0.f, f3 = 0.f;
        float f4 = 0.f, f5 = 0.f, f6 = 0.f, f7 = 0.f;
#pragma unroll
        for (int k = 0; k < 4; k++) {
            uint4 v = *(const uint4*)(Opart + ((size_t)k * T + srow) * CI + kc * 32 + quad * 8);
            f0 += bf2f(v.x & 0xffffu); f1 += bf2f(v.x >> 16);
            f2 += bf2f(v.y & 0xffffu); f3 += bf2f(v.y >> 16);
            f4 += bf2f(v.z & 0xffffu); f5 += bf2f(v.z >> 16);
            f6 += bf2f(v.w & 0xffffu); f7 += bf2f(v.w >> 16);
        }
        union { unsigned int uu[4]; bf16x8 vv; } r;
        r.uu[0] = pk2(f0 * rinv, f1 * rinv);
        r.uu[1] = pk2(f2 * rinv, f3 * rinv);
        r.uu[2] = pk2(f4 * rinv, f5 * rinv);
        r.uu[3] = pk2(f6 * rinv, f7 * rinv);
        yb[kc] = r.vv;
    }

    const unsigned short* wob = wbf + 3 * 32768 + (size_t)oh * 128 * CI;
    f32x4 acc[8];
#pragma unroll
    for (int ot = 0; ot < 8; ot++) acc[ot] = (f32x4){0.f, 0.f, 0.f, 0.f};
#pragma unroll
    for (int kc = 0; kc < 4; kc++) {
#pragma unroll
        for (int ot = 0; ot < 8; ot++) {
            bf16x8 wa = *(const bf16x8*)(wob + (size_t)(ot * 16 + l15) * CI + kc * 32 + quad * 8);
            acc[ot] = MFMA16(wa, yb[kc], acc[ot]);
        }
    }
#pragma unroll
    for (int ot = 0; ot < 8; ot++) {
#pragma unroll
        for (int r = 0; r < 4; r++) {
            int o = oh * 128 + ot * 16 + quad * 4 + r;
            size_t idx = ((size_t)n * CH + o) * NS + sw + l15;
            out[idx] = x[idx] + acc[ot][r] + b_out[o];
        }
    }
}

// ---------------------------------------------------------------------------
extern "C" void kernel_launch(void* const* d_in, const int* in_sizes, int n_in,
                              void* d_out, int out_size, void* d_ws, size_t ws_size,
                              hipStream_t stream) {
    const float* x     = (const float*)d_in[0];
    const float* w_g   = (const float*)d_in[1];
    const float* b_g   = (const float*)d_in[2];
    const float* w_th  = (const float*)d_in[3];
    const float* b_th  = (const float*)d_in[4];
    const float* w_ph  = (const float*)d_in[5];
    const float* b_ph  = (const float*)d_in[6];
    const float* w_out = (const float*)d_in[7];
    const float* b_out = (const float*)d_in[8];
    float* out = (float*)d_out;

    char* ws = (char*)d_ws;
    unsigned short* theta = (unsigned short*)(ws + 0);          //  4 MiB
    unsigned short* phi   = (unsigned short*)(ws + 4194304);    //  4 MiB
    unsigned short* gT    = (unsigned short*)(ws + 8388608);    //  4 MiB
    unsigned short* Opart = (unsigned short*)(ws + 12582912);   // 16 MiB (4 splits bf16)
    float* lbuf  = (float*)(ws + 29360128);                     // 256 KiB
    unsigned short* wbf = (unsigned short*)(ws + 29622272);     // 256 KiB
    float* bsc   = (float*)(ws + 29884416);                     //  1.5 KiB

    wcvt_kernel<<<512, 256, 0, stream>>>(w_g, w_th, w_ph, w_out, b_g, b_th, b_ph, wbf, bsc);
    proj_kernel<<<dim3(64, NB), 512, 0, stream>>>(x, wbf, bsc, theta, phi, gT);
    attn_kernel<<<dim3(16, 32), 256, 0, stream>>>(theta, phi, gT, Opart, lbuf);
    outproj_kernel<<<dim3(64, 2, NB), 256, 0, stream>>>(x, wbf, b_out, Opart, lbuf, out);
}